// Round 6
// baseline (310.390 us; speedup 1.0000x reference)
//
#include <hip/hip_runtime.h>

#define DI __device__ __forceinline__

typedef float  f32x2  __attribute__((ext_vector_type(2)));
typedef float  f32x4  __attribute__((ext_vector_type(4)));
typedef float  f32x16 __attribute__((ext_vector_type(16)));
typedef __bf16 bf16x8 __attribute__((ext_vector_type(8)));
typedef unsigned u32x2 __attribute__((ext_vector_type(2)));
typedef unsigned u32x4 __attribute__((ext_vector_type(4)));

static constexpr int TB   = 2048;   // tokens per batch
static constexpr int NTOK = 8192;   // 4 * 2048
static constexpr int EMB  = 1024;
static constexpr int FQKV = 3072;

// RTNE float -> bf16 bits
DI unsigned short f2bf(float f) {
  union { float f; unsigned u; } v; v.f = f;
  unsigned r = v.u + 0x7FFFu + ((v.u >> 16) & 1u);
  return (unsigned short)(r >> 16);
}

// pack two f32 -> two bf16 in one dword: low16 = a, high16 = b
DI unsigned pack2bf(float a, float b) {
#if __has_builtin(__builtin_amdgcn_cvt_pk_bf16_f32)
  typedef __bf16 bf16x2 __attribute__((ext_vector_type(2)));
  bf16x2 r = __builtin_amdgcn_cvt_pk_bf16_f32(a, b);
  return __builtin_bit_cast(unsigned, r);
#else
  unsigned ua = __builtin_bit_cast(unsigned, a) + 0x8000u;  // round-half-up
  unsigned ub = __builtin_bit_cast(unsigned, b) + 0x8000u;
  return __builtin_amdgcn_perm(ub, ua, 0x07060302u);
#endif
}

// v_permlane32_swap: a' = [a.lo32lanes, b.lo32lanes], b' = [a.hi32lanes, b.hi32lanes]
DI void plswap(unsigned& a, unsigned& b) {
#if __has_builtin(__builtin_amdgcn_permlane32_swap)
  u32x2 r = __builtin_amdgcn_permlane32_swap(a, b, false, false);
  a = r.x; b = r.y;
#else
  const bool hi = (threadIdx.x & 32) != 0;
  unsigned ax = (unsigned)__shfl_xor((int)a, 32);
  unsigned bx = (unsigned)__shfl_xor((int)b, 32);
  unsigned na = hi ? bx : a;
  unsigned nb = hi ? b : ax;
  a = na; b = nb;
#endif
}

DI bf16x8 frag4(unsigned a, unsigned b, unsigned c, unsigned d) {
  u32x4 u = {a, b, c, d};
  return __builtin_bit_cast(bf16x8, u);
}

// async global->LDS, 16B per lane; LDS dest = wave-uniform base + lane*16
DI void gload16(const void* g, void* l) {
  __builtin_amdgcn_global_load_lds(
      (__attribute__((address_space(1))) void*)(g),
      (__attribute__((address_space(3))) void*)(l), 16, 0, 0);
}

// barrier with GUARANTEED pre-drain of this wave's outstanding DMA ops
// (r4 post-mortem: compiler may defer the vmcnt wait past s_barrier, making
// another wave read stale LDS; explicit s_waitcnt(0) closes the race).
DI void syncdrain() {
  __builtin_amdgcn_s_waitcnt(0);
  __syncthreads();
}

// ---------------- fp32 -> bf16 conversion for x, w_qkv, w_out ----------------
__global__ __launch_bounds__(256)
void cvt_kernel(const float4* __restrict__ x, const float4* __restrict__ wq,
                const float4* __restrict__ wo,
                ushort4* __restrict__ xb, ushort4* __restrict__ wqb,
                ushort4* __restrict__ wob) {
  const int i  = blockIdx.x * 256 + threadIdx.x;
  const int nx = NTOK * EMB / 4;       // 2097152
  const int nq = FQKV * EMB / 4;       // 786432
  float4 v; ushort4* dst;
  if (i < nx)           { v = x[i];           dst = xb  + i; }
  else if (i < nx + nq) { v = wq[i - nx];     dst = wqb + (i - nx); }
  else                  { v = wo[i - nx - nq]; dst = wob + (i - nx - nq); }
  ushort4 p;
  p.x = f2bf(v.x); p.y = f2bf(v.y); p.z = f2bf(v.z); p.w = f2bf(v.w);
  *dst = p;
}

// ---------------- 128x128 bf16 GEMM, C = A * Bt^T (both row-major [.,K]) ----
// TRANS path (Q/K and MODE1): swap MFMA operands -> D holds C^T mapping:
// lane = C-row, regs = 4 consecutive C-cols -> vectorized ushort4/float4 store.
// V path keeps the r1-verified orientation (regs = 4 consecutive tokens).
template <int MODE>
__global__ __launch_bounds__(256)
void gemm_bt(const unsigned short* __restrict__ A,
             const unsigned short* __restrict__ Bt,
             const int K,
             unsigned short* __restrict__ qk,
             unsigned short* __restrict__ vT,
             float* __restrict__ outp) {
  __shared__ unsigned short sA[128 * 32];
  __shared__ unsigned short sB[128 * 32];
  const int tid  = threadIdx.x;
  const int w    = tid >> 6;
  const int l    = tid & 63;
  const int quad = l >> 4;
  const int lr   = l & 15;
  const int n0   = blockIdx.x * 128;
  const int m0   = blockIdx.y * 128;
  const int wm   = (w >> 1) * 64;
  const int wn   = (w & 1) * 64;
  const bool TRANS = (MODE == 1) || (n0 < 2048);

  f32x4 acc[4][4];
#pragma unroll
  for (int i = 0; i < 4; ++i)
#pragma unroll
    for (int j = 0; j < 4; ++j) acc[i][j] = {0.f, 0.f, 0.f, 0.f};

  const int srow = l >> 2;
  const int sg   = (l & 3) ^ ((l >> 3) & 3);
  const unsigned short* gA = A  + (long)(m0 + w * 32 + srow) * K + sg * 8;
  const unsigned short* gB = Bt + (long)(n0 + w * 32 + srow) * K + sg * 8;
  unsigned short* lA = sA + w * 1024;
  unsigned short* lB = sB + w * 1024;
  const int swz = (lr >> 1) & 3;

  for (int k0 = 0; k0 < K; k0 += 32) {
    gload16(gA + k0,          lA);
    gload16(gA + k0 + 16 * K, lA + 512);
    gload16(gB + k0,          lB);
    gload16(gB + k0 + 16 * K, lB + 512);
    syncdrain();
    bf16x8 af[4], bfr[4];
#pragma unroll
    for (int rt = 0; rt < 4; ++rt)
      af[rt] = *(const bf16x8*)(sA + (wm + rt * 16 + lr) * 32 + (quad ^ swz) * 8);
#pragma unroll
    for (int ct = 0; ct < 4; ++ct)
      bfr[ct] = *(const bf16x8*)(sB + (wn + ct * 16 + lr) * 32 + (quad ^ swz) * 8);
    if (TRANS) {
#pragma unroll
      for (int rt = 0; rt < 4; ++rt)
#pragma unroll
        for (int ct = 0; ct < 4; ++ct)
          acc[rt][ct] = __builtin_amdgcn_mfma_f32_16x16x32_bf16(bfr[ct], af[rt],
                                                                acc[rt][ct], 0, 0, 0);
    } else {
#pragma unroll
      for (int rt = 0; rt < 4; ++rt)
#pragma unroll
        for (int ct = 0; ct < 4; ++ct)
          acc[rt][ct] = __builtin_amdgcn_mfma_f32_16x16x32_bf16(af[rt], bfr[ct],
                                                                acc[rt][ct], 0, 0, 0);
    }
    __syncthreads();
  }

  if (MODE == 0) {
    if (n0 < 2048) {
      // TRANS mapping: lane = C-row (m = lr), regs = 4 consecutive cols
      const float qs = (n0 < 1024) ? 0.18033688011112042f : 1.0f;
#pragma unroll
      for (int rt = 0; rt < 4; ++rt) {
        const int row = m0 + wm + rt * 16 + lr;
#pragma unroll
        for (int ct = 0; ct < 4; ++ct) {
          const int col = n0 + wn + ct * 16 + quad * 4;
          ushort4 p;
          p.x = f2bf(acc[rt][ct][0] * qs); p.y = f2bf(acc[rt][ct][1] * qs);
          p.z = f2bf(acc[rt][ct][2] * qs); p.w = f2bf(acc[rt][ct][3] * qs);
          *(ushort4*)(qk + (long)row * 2048 + col) = p;
        }
      }
    } else {
      // V (non-TRANS, r1-verified): regs = 4 consecutive tokens
#pragma unroll
      for (int rt = 0; rt < 4; ++rt) {
        const int tok = m0 + wm + rt * 16 + quad * 4;
        const int bb  = tok >> 11, tt = tok & 2047;
#pragma unroll
        for (int ct = 0; ct < 4; ++ct) {
          const int fv = n0 - 2048 + wn + ct * 16 + lr;  // h*64+d
          ushort4 p;
          p.x = f2bf(acc[rt][ct][0]); p.y = f2bf(acc[rt][ct][1]);
          p.z = f2bf(acc[rt][ct][2]); p.w = f2bf(acc[rt][ct][3]);
          *(ushort4*)(vT + ((long)(bb * 1024 + fv)) * 2048 + tt) = p;
        }
      }
    }
  } else {
    // TRANS fp32 epilogue: float4 stores
#pragma unroll
    for (int rt = 0; rt < 4; ++rt) {
      const int row = m0 + wm + rt * 16 + lr;
#pragma unroll
      for (int ct = 0; ct < 4; ++ct) {
        const int col = n0 + wn + ct * 16 + quad * 4;
        *(f32x4*)(outp + (long)row * 1024 + col) = acc[rt][ct];
      }
    }
  }
}

// ---------------- flash attention v6: 128-key tiles + MFMA rowsums ----------
// Block = 256 queries (4 waves x 64q) for one (b,h); grid (bh, qtile) keeps
// all q-tiles of a (b,h) on one XCD. K/V double-buffered in 64 KiB LDS
// (2 blocks/CU x 64 KiB = 128 <= 160 KiB). Rowsums accumulated on the matrix
// pipe via mfma(P, ones) -> same reg<->q-row layout as oacc, no reductions.
__global__ __launch_bounds__(256, 2)
void attn_kernel(const unsigned short* __restrict__ qk,
                 const unsigned short* __restrict__ vT,
                 unsigned short* __restrict__ attnb) {
  __shared__ unsigned short sK[2][128 * 64];  // [key][d], 8x16B granules/row
  __shared__ unsigned short sV[2][64 * 128];  // [d][t], 16x16B granules/row
  const int tid = threadIdx.x;
  const int w   = tid >> 6;
  const int l   = tid & 63;
  const int l31 = l & 31;
  const int lh  = l >> 5;            // lane half
  const int h8  = lh * 8;            // k-offset of this lane-half in A/B frags
  const int bh  = blockIdx.x;
  const int hh  = bh & 15;
  const long tokbase = (long)(bh >> 4) * TB;
  const int qbase = blockIdx.y * 256 + w * 64;

  // Q fragments (B operand) for both 32-q sets: Q[q][d = s*16 + h8 + j]
  bf16x8 qf[2][4];
#pragma unroll
  for (int qs = 0; qs < 2; ++qs) {
    const unsigned short* qptr =
        qk + (tokbase + qbase + qs * 32 + l31) * 2048 + hh * 64 + h8;
#pragma unroll
    for (int s = 0; s < 4; ++s) qf[qs][s] = *(const bf16x8*)(qptr + s * 16);
  }

  // K staging: wave w covers keys w*32..w*32+31; instr = 8 rows x 8 granules.
  // LDS slot spos of row r holds global granule spos ^ (r&7).
  const int srow8 = l >> 3;
  const int g8    = (l & 7) ^ srow8;
  const unsigned short* kbase =
      qk + (tokbase + w * 32 + srow8) * 2048 + 1024 + hh * 64 + g8 * 8;
  // V staging: wave w covers d rows w*16..w*16+15; instr = 4 rows x 16 granules.
  // slot spos of row d holds global granule spos ^ (d&15); d&15 = i*4 + (l>>4).
  const int srow4 = l >> 4;
  const unsigned short* vbase_i[4];
#pragma unroll
  for (int i = 0; i < 4; ++i) {
    const int gi = (l & 15) ^ (i * 4 + srow4);
    vbase_i[i] = vT + ((long)bh * 64 + w * 16 + i * 4 + srow4) * 2048 + gi * 8;
  }

  f32x16 oacc[2][2] = {{{}, {}}, {{}, {}}};
  f32x16 lacc[2] = {{}, {}};
  bf16x8 ones;
#pragma unroll
  for (int i = 0; i < 8; ++i) ones[i] = (__bf16)1.0f;

  // stage tile 0 into buf 0
#pragma unroll
  for (int i = 0; i < 4; ++i) {
    gload16(kbase + (long)(i * 8) * 2048, &sK[0][(w * 32 + i * 8) * 64]);
    gload16(vbase_i[i],                   &sV[0][(w * 16 + i * 4) * 128]);
  }
  syncdrain();

  for (int t = 0; t < 16; ++t) {
    const int buf = t & 1;
    if (t + 1 < 16) {
      const int k0 = (t + 1) * 128;
      const int nb = buf ^ 1;
#pragma unroll
      for (int i = 0; i < 4; ++i) {
        gload16(kbase + (long)(k0 + i * 8) * 2048, &sK[nb][(w * 32 + i * 8) * 64]);
        gload16(vbase_i[i] + k0,                   &sV[nb][(w * 16 + i * 4) * 128]);
      }
    }
    const unsigned short* bK = sK[buf];
    const unsigned short* bV = sV[buf];

#pragma unroll
    for (int G = 0; G < 4; ++G) {
      // S^T for both q-sets: A = K rows (32 keys of this group), read once
      f32x16 sacc[2] = {{}, {}};
#pragma unroll
      for (int s = 0; s < 4; ++s) {
        const int key = G * 32 + l31;
        const int p   = (s * 2 + lh) ^ (key & 7);
        const bf16x8 kf = *(const bf16x8*)(bK + key * 64 + p * 8);
        sacc[0] = __builtin_amdgcn_mfma_f32_32x32x16_bf16(kf, qf[0][s], sacc[0], 0, 0, 0);
        sacc[1] = __builtin_amdgcn_mfma_f32_32x32x16_bf16(kf, qf[1][s], sacc[1], 0, 0, 0);
      }
      // softmax numerators + repack to A-frag key order, per q-set
      bf16x8 pp[2][2];
#pragma unroll
      for (int qs = 0; qs < 2; ++qs) {
        float e[16];
#pragma unroll
        for (int i = 0; i < 16; ++i) e[i] = __builtin_amdgcn_exp2f(sacc[qs][i]);
        unsigned d[8];
#pragma unroll
        for (int i = 0; i < 8; ++i) d[i] = pack2bf(e[2 * i], e[2 * i + 1]);
        plswap(d[0], d[2]); plswap(d[1], d[3]);
        plswap(d[4], d[6]); plswap(d[5], d[7]);
        pp[qs][0] = frag4(d[0], d[1], d[2], d[3]);
        pp[qs][1] = frag4(d[4], d[5], d[6], d[7]);
      }
      // rowsums on the matrix pipe: lacc[q] += sum_k P[q][k]
      lacc[0] = __builtin_amdgcn_mfma_f32_32x32x16_bf16(pp[0][0], ones, lacc[0], 0, 0, 0);
      lacc[0] = __builtin_amdgcn_mfma_f32_32x32x16_bf16(pp[0][1], ones, lacc[0], 0, 0, 0);
      lacc[1] = __builtin_amdgcn_mfma_f32_32x32x16_bf16(pp[1][0], ones, lacc[1], 0, 0, 0);
      lacc[1] = __builtin_amdgcn_mfma_f32_32x32x16_bf16(pp[1][1], ones, lacc[1], 0, 0, 0);
      // O += P V: V-frags read once per (G,sub), reused by both q-sets
#pragma unroll
      for (int sub = 0; sub < 2; ++sub) {
        const int gt = G * 4 + sub * 2 + lh;          // key-granule index
        const int p  = gt ^ (l31 & 15);               // (32+l31)&15 == l31&15
        const bf16x8 vf0 = *(const bf16x8*)(bV + l31 * 128 + p * 8);
        const bf16x8 vf1 = *(const bf16x8*)(bV + (32 + l31) * 128 + p * 8);
#pragma unroll
        for (int qs = 0; qs < 2; ++qs) {
          oacc[qs][0] = __builtin_amdgcn_mfma_f32_32x32x16_bf16(pp[qs][sub], vf0, oacc[qs][0], 0, 0, 0);
          oacc[qs][1] = __builtin_amdgcn_mfma_f32_32x32x16_bf16(pp[qs][sub], vf1, oacc[qs][1], 0, 0, 0);
        }
      }
    }
    syncdrain();
  }

  // normalize: lacc has the SAME reg<->q-row mapping as oacc; no reductions
#pragma unroll
  for (int qs = 0; qs < 2; ++qs) {
#pragma unroll
    for (int r = 0; r < 16; ++r) {
      const float sc = 1.0f / lacc[qs][r];
      const int row = (r & 3) + 8 * (r >> 2) + 4 * lh;  // q within 32-q set
      const long base = (tokbase + qbase + qs * 32 + row) * 1024 + hh * 64;
      attnb[base + l31]      = f2bf(oacc[qs][0][r] * sc);
      attnb[base + 32 + l31] = f2bf(oacc[qs][1][r] * sc);
    }
  }
}

// ---------------------------------------------------------------------------
extern "C" void kernel_launch(void* const* d_in, const int* in_sizes, int n_in,
                              void* d_out, int out_size, void* d_ws, size_t ws_size,
                              hipStream_t stream) {
  const float* x    = (const float*)d_in[0];
  const float* wqkv = (const float*)d_in[1];
  const float* wout = (const float*)d_in[2];
  float* outp = (float*)d_out;

  unsigned short* xb    = (unsigned short*)d_ws;          // 8192*1024
  unsigned short* wqkvb = xb    + (long)NTOK * EMB;       // 3072*1024
  unsigned short* woutb = wqkvb + (long)FQKV * EMB;       // 1024*1024
  unsigned short* qkb   = woutb + (long)EMB * EMB;        // 8192*2048 (Q|K)
  unsigned short* vTb   = qkb   + (long)NTOK * 2048;      // 4*16*64*2048
  unsigned short* attnb = vTb   + (long)4 * 16 * 64 * TB; // 8192*1024

  cvt_kernel<<<12288, 256, 0, stream>>>(
      (const float4*)x, (const float4*)wqkv, (const float4*)wout,
      (ushort4*)xb, (ushort4*)wqkvb, (ushort4*)woutb);

  gemm_bt<0><<<dim3(24, 64), 256, 0, stream>>>(xb, wqkvb, EMB, qkb, vTb, nullptr);

  // attention: grid (bh, qtile) -> XCD-local K/V reuse
  attn_kernel<<<dim3(64, 8), 256, 0, stream>>>(qkb, vTb, attnb);

  gemm_bt<1><<<dim3(8, 64), 256, 0, stream>>>(attnb, woutb, EMB, nullptr, nullptr, outp);
}